// Round 13
// baseline (108.613 us; speedup 1.0000x reference)
//
#include <hip/hip_runtime.h>

#define NTHREADS 256

typedef __attribute__((ext_vector_type(8))) short bf16x8;
typedef __attribute__((ext_vector_type(4))) short bf16x4;
typedef __attribute__((ext_vector_type(4))) float f32x4;
typedef __attribute__((ext_vector_type(2))) unsigned uint2v;
typedef __attribute__((ext_vector_type(4))) unsigned uint4v;

constexpr int kB = 16, kS = 2048, kD = 128;
constexpr int QBLK = 128, KBLK = 32;
constexpr int MSTRIDE = 36;          // mask row stride (bytes): 2 lanes/bank reads
constexpr int BUFSZ = 20992;         // K 8192 + VT 8192 + mask 4608
constexpr float kNegMax = -3.402823466e38f;
constexpr float kMClamp = -1e30f;    // running-max floor (log2 domain)
constexpr float kDeferThr = 8.0f;    // T13: skip rescale if pmax <= m + 8 (P <= 2^8)

__device__ __forceinline__ unsigned cvt_pk(float lo, float hi) {
    unsigned r;
    asm("v_cvt_pk_bf16_f32 %0, %1, %2" : "=v"(r) : "v"(lo), "v"(hi));
    return r;
}

// K=16 PV MFMA: A[m=l15][k=lg*4+j], B[k=lg*4+j][n=l15] -- P lands here in-lane (R12-proven).
__device__ __forceinline__ f32x4 mfma16(bf16x4 a, bf16x4 b, f32x4 c) {
#if __has_builtin(__builtin_amdgcn_mfma_f32_16x16x16bf16_1k)
    return __builtin_amdgcn_mfma_f32_16x16x16bf16_1k(a, b, c, 0, 0, 0);
#else
    asm("v_mfma_f32_16x16x16_bf16 %0, %1, %2, %0" : "+v"(c) : "v"(a), "v"(b));
    return c;
#endif
}

// K swizzle (R4/R7-proven): 256B rows, key row&7
#define SWZ(bytecol, row) ((bytecol) ^ (((row) & 7) << 4))
// VT paired-row layout (R10-proven): d and d+64 share a 128B row, key (d&7)^((d>>2)&7)
#define KEYV(d) ((((d) & 7) ^ (((d) >> 2) & 7)) & 7)

// SPLIT=1: full K per block (grid 256, 64 rounds), direct store.
// SPLIT=2: k-split halves (grid 512, 32 rounds), partials to ws + merge.
template<int SPLIT>
__global__ __launch_bounds__(NTHREADS, 2)
void attn_fwd(const float* __restrict__ q, const float* __restrict__ k,
              const float* __restrict__ v, const int* __restrict__ mask,
              float* __restrict__ out, float* __restrict__ ws)
{
    // Double-buffered: 2 x {K 8K | VT 8K | mask 4.6K} = 42 KB
    __shared__ __align__(16) char smem[2 * BUFSZ];

    const int tid = threadIdx.x, lane = tid & 63, w = tid >> 6;
    const int l15 = lane & 15, lg = lane >> 4;

    // XCD-aware swizzle: contiguous swz chunk (whole batches) per XCD
    const int bid = (int)blockIdx.x;
    int b, qbase, kbase;
    if (SPLIT == 1) {
        int swz = (bid & 7) * 32 + (bid >> 3);
        b = swz >> 4; qbase = (swz & 15) * QBLK; kbase = 0;
    } else {
        int swz = (bid & 7) * 64 + (bid >> 3);
        b = swz >> 5;
        int rem = swz & 31;
        qbase = (rem >> 1) * QBLK;       // adjacent swz pairs share the q-tile
        kbase = (rem & 1) * (kS / 2);
    }
    const int nrounds = (SPLIT == 1) ? (kS / KBLK) : (kS / KBLK / 2);  // 64 / 32 (even)

    // ---- hoist Q^T fragments; pre-scale folds 1/sqrt(D) AND log2(e) (exp2 softmax) ----
    const float scale = 0.08838834764831845f * 1.4426950408889634f;
    bf16x8 qf[2][4];
    #pragma unroll
    for (int qs = 0; qs < 2; ++qs) {
        const float* qp = q + ((size_t)(b*kS + qbase + w*32 + qs*16 + l15)) * kD;
        #pragma unroll
        for (int kk = 0; kk < 4; ++kk) {
            float4 a = *(const float4*)(qp + kk*32 + lg*8);
            float4 c = *(const float4*)(qp + kk*32 + lg*8 + 4);
            uint4v pk = { cvt_pk(a.x*scale, a.y*scale), cvt_pk(a.z*scale, a.w*scale),
                          cvt_pk(c.x*scale, c.y*scale), cvt_pk(c.z*scale, c.w*scale) };
            qf[qs][kk] = __builtin_bit_cast(bf16x8, pk);
        }
    }

    // acc[qs][dblk] = O^T[d = dblk*16 + lg*4 + i][q = l15] for q-subtile qs
    f32x4 acc[2][8];
    #pragma unroll
    for (int qs = 0; qs < 2; ++qs)
        #pragma unroll
        for (int d = 0; d < 8; ++d) acc[qs][d] = f32x4{0.f,0.f,0.f,0.f};
    float m_r[2] = {kMClamp, kMClamp};
    float l_r[2] = {0.f, 0.f};

    const float* kbat = k + (size_t)b * kS * kD;
    const float* vbat = v + (size_t)b * kS * kD;
    const int*   mbat = mask + ((size_t)b * kS + qbase) * kS;

    const int kg = tid >> 5, dg = tid & 31;   // V staging assignment

    // ---- T14 prefetch registers (48 total) ----
    float4 kreg[2][2];   // K: 2 chunks x 8 floats
    float4 vreg[4];      // V: one 4k x 4d block
    int4   mreg[4];      // mask: 4 int4 (128 rows x 32 ints / 256 thr)

    auto LOAD = [&](int kt0) {
        #pragma unroll
        for (int c = 0; c < 2; ++c) {
            int chunk = c * 256 + tid;
            int row = chunk >> 4, col8 = chunk & 15;
            const float4* ptr = (const float4*)(kbat + (size_t)(kt0 + row)*kD + col8*8);
            kreg[c][0] = ptr[0];
            kreg[c][1] = ptr[1];
        }
        #pragma unroll
        for (int r = 0; r < 4; ++r)
            vreg[r] = *(const float4*)(vbat + (size_t)(kt0 + kg*4 + r)*kD + dg*4);
        #pragma unroll
        for (int c = 0; c < 4; ++c) {
            int idx = c * 256 + tid;
            int mrow = idx >> 3, mc4 = idx & 7;
            mreg[c] = *(const int4*)(mbat + (size_t)mrow*kS + kt0 + mc4*4);
        }
    };

    auto STORE = [&](char* Kd, char* VTd, unsigned char* Md) {
        #pragma unroll
        for (int c = 0; c < 2; ++c) {
            int chunk = c * 256 + tid;
            int row = chunk >> 4, col8 = chunk & 15;
            uint4v pk = { cvt_pk(kreg[c][0].x, kreg[c][0].y), cvt_pk(kreg[c][0].z, kreg[c][0].w),
                          cvt_pk(kreg[c][1].x, kreg[c][1].y), cvt_pk(kreg[c][1].z, kreg[c][1].w) };
            *(uint4v*)(Kd + row*256 + SWZ(col8*16, row)) = pk;
        }
        #pragma unroll
        for (int jj = 0; jj < 4; ++jj) {
            int d = dg * 4 + jj;             // VT: d 0..127, k-cols kg*4..+3
            int col = (d >> 6) * 64 + kg * 8;
            uint2v pk = { cvt_pk((&vreg[0].x)[jj], (&vreg[1].x)[jj]),
                          cvt_pk((&vreg[2].x)[jj], (&vreg[3].x)[jj]) };
            *(uint2v*)(VTd + (d & 63)*128 + (col ^ (KEYV(d) << 4))) = pk;
        }
        #pragma unroll
        for (int c = 0; c < 4; ++c) {
            int idx = c * 256 + tid;
            int mrow = idx >> 3, mc4 = idx & 7;
            unsigned pk = (unsigned)(mreg[c].x != 0)
                        | ((unsigned)(mreg[c].y != 0) << 8)
                        | ((unsigned)(mreg[c].z != 0) << 16)
                        | ((unsigned)(mreg[c].w != 0) << 24);
            *(unsigned*)(Md + mrow*MSTRIDE + mc4*4) = pk;
        }
    };

    // One round: LOAD(t+1) issue -> QK/softmax/PV from buf A -> STORE into buf B -> barrier
    auto ROUND = [&](char* Kb, char* VTb, unsigned char* Mb,
                     char* Kn, char* VTn, unsigned char* Mn, int t) {
        const bool has_next = (t + 1 < nrounds);
        if (has_next) LOAD(kbase + (t + 1) * KBLK);

        // ---- S^T = K · Q^T : z[qs][kt][i] = S[k=kt*16+lg*4+i][q=l15] ----
        f32x4 z[2][2];
        #pragma unroll
        for (int qs = 0; qs < 2; ++qs)
            #pragma unroll
            for (int kt = 0; kt < 2; ++kt) z[qs][kt] = f32x4{0.f,0.f,0.f,0.f};
        __builtin_amdgcn_s_setprio(1);
        #pragma unroll
        for (int kt = 0; kt < 2; ++kt) {
            bf16x8 kf[4];
            int krow = kt*16 + l15;
            #pragma unroll
            for (int kk = 0; kk < 4; ++kk)
                kf[kk] = *(const bf16x8*)(Kb + krow*256 + SWZ(kk*64 + lg*16, krow));
            #pragma unroll
            for (int qs = 0; qs < 2; ++qs)
                #pragma unroll
                for (int kk = 0; kk < 4; ++kk)
                    z[qs][kt] = __builtin_amdgcn_mfma_f32_16x16x32_bf16(kf[kk], qf[qs][kk], z[qs][kt], 0, 0, 0);
        }
        __builtin_amdgcn_s_setprio(0);

        // ---- mask + in-lane online softmax (log2 domain); P packs in-place for K=16 PV ----
        bf16x4 pfA[2], pfB[2];
        #pragma unroll
        for (int qs = 0; qs < 2; ++qs) {
            const int mrowb = (w*32 + qs*16 + l15) * MSTRIDE;
            float mx = kNegMax;
            #pragma unroll
            for (int kt = 0; kt < 2; ++kt) {
                unsigned nib = *(const unsigned*)(Mb + mrowb + kt*16 + lg*4);
                #pragma unroll
                for (int i = 0; i < 4; ++i) {
                    float sv = ((nib >> (8*i)) & 0xFFu) ? kNegMax : z[qs][kt][i];
                    z[qs][kt][i] = sv;
                    mx = fmaxf(mx, sv);
                }
            }
            mx = fmaxf(mx, __shfl_xor(mx, 16));
            mx = fmaxf(mx, __shfl_xor(mx, 32));
            if (!__all(mx <= m_r[qs] + kDeferThr)) {       // wave-uniform branch
                float mnew = fmaxf(m_r[qs], mx);
                float corr = exp2f(m_r[qs] - mnew);
                l_r[qs] *= corr;
                #pragma unroll
                for (int d = 0; d < 8; ++d) acc[qs][d] *= corr;
                m_r[qs] = mnew;
            }
            float p00 = exp2f(z[qs][0][0] - m_r[qs]);
            float p01 = exp2f(z[qs][0][1] - m_r[qs]);
            float p02 = exp2f(z[qs][0][2] - m_r[qs]);
            float p03 = exp2f(z[qs][0][3] - m_r[qs]);
            float p10 = exp2f(z[qs][1][0] - m_r[qs]);
            float p11 = exp2f(z[qs][1][1] - m_r[qs]);
            float p12 = exp2f(z[qs][1][2] - m_r[qs]);
            float p13 = exp2f(z[qs][1][3] - m_r[qs]);
            float rs = ((p00 + p01) + (p02 + p03)) + ((p10 + p11) + (p12 + p13));
            rs += __shfl_xor(rs, 16);
            rs += __shfl_xor(rs, 32);
            l_r[qs] += rs;
            uint2v pa = { cvt_pk(p00, p01), cvt_pk(p02, p03) };   // B[k=lg*4+j][q=l15], kt0
            uint2v pb = { cvt_pk(p10, p11), cvt_pk(p12, p13) };   // kt1
            pfA[qs] = __builtin_bit_cast(bf16x4, pa);
            pfB[qs] = __builtin_bit_cast(bf16x4, pb);
        }

        // ---- O^T += V^T · P^T as two K=16 MFMAs (no P LDS, no cross-lane) ----
        __builtin_amdgcn_s_setprio(1);
        #pragma unroll
        for (int dblk = 0; dblk < 8; ++dblk) {
            int d = dblk*16 + l15;
            int rowb = (d & 63) * 128;
            int half = (d >> 6) * 64;
            int key = KEYV(d) << 4;
            bf16x4 vf0 = *(const bf16x4*)(VTb + rowb + ((half + lg*8) ^ key));
            bf16x4 vf1 = *(const bf16x4*)(VTb + rowb + ((half + 32 + lg*8) ^ key));
            #pragma unroll
            for (int qs = 0; qs < 2; ++qs) {
                acc[qs][dblk] = mfma16(vf0, pfA[qs], acc[qs][dblk]);
                acc[qs][dblk] = mfma16(vf1, pfB[qs], acc[qs][dblk]);
            }
        }
        __builtin_amdgcn_s_setprio(0);

        if (has_next) STORE(Kn, VTn, Mn);   // vmcnt wait covered by the whole round
        __syncthreads();
    };

    char* K0 = smem,          * VT0 = smem + 8192;
    unsigned char* M0 = (unsigned char*)(smem + 16384);
    char* K1 = smem + BUFSZ,  * VT1 = smem + BUFSZ + 8192;
    unsigned char* M1 = (unsigned char*)(smem + BUFSZ + 16384);

    LOAD(kbase);
    STORE(K0, VT0, M0);
    __syncthreads();

    for (int t = 0; t < nrounds; t += 2) {
        ROUND(K0, VT0, M0, K1, VT1, M1, t);
        ROUND(K1, VT1, M1, K0, VT0, M0, t + 1);
    }

    if (SPLIT == 1) {
        #pragma unroll
        for (int qs = 0; qs < 2; ++qs) {
            float inv = 1.0f / l_r[qs];
            float* op = out + ((size_t)(b*kS + qbase + w*32 + qs*16 + l15)) * kD;
            #pragma unroll
            for (int dblk = 0; dblk < 8; ++dblk) {
                float4 r;
                r.x = acc[qs][dblk][0] * inv;
                r.y = acc[qs][dblk][1] * inv;
                r.z = acc[qs][dblk][2] * inv;
                r.w = acc[qs][dblk][3] * inv;
                *(float4*)(op + dblk*16 + lg*4) = r;
            }
        }
    } else {
        const int half = (kbase != 0);
        #pragma unroll
        for (int qs = 0; qs < 2; ++qs) {
            const size_t row = (size_t)half * (kB*kS) + (size_t)b*kS + qbase + w*32 + qs*16 + l15;
            float* op = ws + row * kD;
            #pragma unroll
            for (int dblk = 0; dblk < 8; ++dblk) {
                float4 r;
                r.x = acc[qs][dblk][0]; r.y = acc[qs][dblk][1];
                r.z = acc[qs][dblk][2]; r.w = acc[qs][dblk][3];
                *(float4*)(op + dblk*16 + lg*4) = r;
            }
            if (lg == 0) {
                float* ml = ws + (size_t)2*kB*kS*kD;
                ml[row*2 + 0] = m_r[qs];
                ml[row*2 + 1] = l_r[qs];
            }
        }
    }
}

// merge the two k-halves (m is log2-domain): out = (o0*e0 + o1*e1) / (l0*e0 + l1*e1)
__global__ __launch_bounds__(NTHREADS)
void attn_merge(const float* __restrict__ ws, float* __restrict__ out)
{
    const float* ml = ws + (size_t)2*kB*kS*kD;
    const int tid = threadIdx.x;
    const size_t r = (size_t)blockIdx.x * 8 + (tid >> 5);
    const int c = (tid & 31) * 4;
    float m0 = ml[r*2 + 0],               l0 = ml[r*2 + 1];
    float m1 = ml[((size_t)kB*kS + r)*2], l1 = ml[((size_t)kB*kS + r)*2 + 1];
    float mS = fmaxf(m0, m1);
    float e0 = exp2f(m0 - mS), e1 = exp2f(m1 - mS);
    float inv = 1.0f / (l0*e0 + l1*e1);
    float4 o0 = *(const float4*)(ws + r*kD + c);
    float4 o1 = *(const float4*)(ws + (size_t)kB*kS*kD + r*kD + c);
    float4 rr;
    rr.x = (o0.x*e0 + o1.x*e1) * inv;
    rr.y = (o0.y*e0 + o1.y*e1) * inv;
    rr.z = (o0.z*e0 + o1.z*e1) * inv;
    rr.w = (o0.w*e0 + o1.w*e1) * inv;
    *(float4*)(out + r*kD + c) = rr;
}

extern "C" void kernel_launch(void* const* d_in, const int* in_sizes, int n_in,
                              void* d_out, int out_size, void* d_ws, size_t ws_size,
                              hipStream_t stream) {
    const float* q = (const float*)d_in[0];
    const float* k = (const float*)d_in[1];
    const float* v = (const float*)d_in[2];
    const int* mask = (const int*)d_in[3];
    float* out = (float*)d_out;
    const size_t wsNeeded = (size_t)2*kB*kS*kD*4 + (size_t)2*kB*kS*2*4;
    if (ws_size >= wsNeeded) {
        attn_fwd<2><<<dim3(kB * (kS/QBLK) * 2), dim3(NTHREADS), 0, stream>>>(
            q, k, v, mask, out, (float*)d_ws);
        attn_merge<<<dim3(kB*kS/8), dim3(NTHREADS), 0, stream>>>((const float*)d_ws, out);
    } else {
        attn_fwd<1><<<dim3(kB * (kS/QBLK)), dim3(NTHREADS), 0, stream>>>(
            q, k, v, mask, out, nullptr);
    }
}

// Round 17
// 105.826 us; speedup vs baseline: 1.0263x; 1.0263x over previous
//
#include <hip/hip_runtime.h>

#define NTHREADS 256

typedef __attribute__((ext_vector_type(8))) short bf16x8;
typedef __attribute__((ext_vector_type(4))) short bf16x4;
typedef __attribute__((ext_vector_type(4))) float f32x4;
typedef __attribute__((ext_vector_type(2))) unsigned uint2v;
typedef __attribute__((ext_vector_type(4))) unsigned uint4v;

constexpr int kB = 16, kS = 2048, kD = 128;
constexpr int QBLK = 128, KBLK = 32;
constexpr int MSTRIDE = 36;          // mask row stride (bytes): 2 lanes/bank reads
constexpr float kNegMax = -3.402823466e38f;
constexpr float kMClamp = -1e30f;    // running-max floor (log2 domain)
constexpr float kDeferThr = 8.0f;    // T13: skip rescale if pmax <= m + 8 (P <= 2^8)

__device__ __forceinline__ unsigned cvt_pk(float lo, float hi) {
    unsigned r;
    asm("v_cvt_pk_bf16_f32 %0, %1, %2" : "=v"(r) : "v"(lo), "v"(hi));
    return r;
}

// K=16 PV MFMA: A[m=l15][k=lg*4+j], B[k=lg*4+j][n=l15] -- P lands here in-lane (R12-proven).
__device__ __forceinline__ f32x4 mfma16(bf16x4 a, bf16x4 b, f32x4 c) {
#if __has_builtin(__builtin_amdgcn_mfma_f32_16x16x16bf16_1k)
    return __builtin_amdgcn_mfma_f32_16x16x16bf16_1k(a, b, c, 0, 0, 0);
#else
    asm("v_mfma_f32_16x16x16_bf16 %0, %1, %2, %0" : "+v"(c) : "v"(a), "v"(b));
    return c;
#endif
}

// K swizzle (R4/R7-proven): 256B rows, key row&7
#define SWZ(bytecol, row) ((bytecol) ^ (((row) & 7) << 4))
// VT paired-row layout (R10-proven): d and d+64 share a 128B row, key (d&7)^((d>>2)&7)
#define KEYV(d) ((((d) & 7) ^ (((d) >> 2) & 7)) & 7)

// SPLIT=1: full K per block (grid 256, 64 rounds), direct store.
// SPLIT=2: k-split halves (grid 512, 32 rounds), partials to ws + merge.
template<int SPLIT>
__global__ __launch_bounds__(NTHREADS, 2)
void attn_fwd(const float* __restrict__ q, const float* __restrict__ k,
              const float* __restrict__ v, const int* __restrict__ mask,
              float* __restrict__ out, float* __restrict__ ws)
{
    // LDS: K 8K | VT 8K | mask 128x36=4.6K => 21 KB (P lives in registers)
    __shared__ __align__(16) char smem[20992];
    char* K_lds  = smem;              // [32 kv][128 d] bf16, 256B rows, SWZ
    char* VT_lds = smem + 8192;       // [64 rows][128B]: row d&63, half d>>6, KEYV
    unsigned char* M_lds = (unsigned char*)(smem + 16384);  // [128 q][36] bytes

    const int tid = threadIdx.x, lane = tid & 63, w = tid >> 6;
    const int l15 = lane & 15, lg = lane >> 4;

    // XCD-aware swizzle: contiguous swz chunk (whole batches) per XCD
    const int bid = (int)blockIdx.x;
    int b, qbase, kbase;
    if (SPLIT == 1) {
        int swz = (bid & 7) * 32 + (bid >> 3);
        b = swz >> 4; qbase = (swz & 15) * QBLK; kbase = 0;
    } else {
        int swz = (bid & 7) * 64 + (bid >> 3);
        b = swz >> 5;
        int rem = swz & 31;
        qbase = (rem >> 1) * QBLK;       // adjacent swz pairs share the q-tile
        kbase = (rem & 1) * (kS / 2);
    }
    const int nrounds = (SPLIT == 1) ? (kS / KBLK) : (kS / KBLK / 2);

    // ---- hoist Q^T fragments; pre-scale folds 1/sqrt(D) AND log2(e) (exp2 softmax) ----
    const float scale = 0.08838834764831845f * 1.4426950408889634f;
    bf16x8 qf[2][4];
    #pragma unroll
    for (int qs = 0; qs < 2; ++qs) {
        const float* qp = q + ((size_t)(b*kS + qbase + w*32 + qs*16 + l15)) * kD;
        #pragma unroll
        for (int kk = 0; kk < 4; ++kk) {
            float4 a = *(const float4*)(qp + kk*32 + lg*8);
            float4 c = *(const float4*)(qp + kk*32 + lg*8 + 4);
            uint4v pk = { cvt_pk(a.x*scale, a.y*scale), cvt_pk(a.z*scale, a.w*scale),
                          cvt_pk(c.x*scale, c.y*scale), cvt_pk(c.z*scale, c.w*scale) };
            qf[qs][kk] = __builtin_bit_cast(bf16x8, pk);
        }
    }

    // acc[qs][dblk] = O^T[d = dblk*16 + lg*4 + i][q = l15] for q-subtile qs
    f32x4 acc[2][8];
    #pragma unroll
    for (int qs = 0; qs < 2; ++qs)
        #pragma unroll
        for (int d = 0; d < 8; ++d) acc[qs][d] = f32x4{0.f,0.f,0.f,0.f};
    float m_r[2] = {kMClamp, kMClamp};
    float l_r[2] = {0.f, 0.f};

    const float* kbat = k + (size_t)b * kS * kD;
    const float* vbat = v + (size_t)b * kS * kD;
    const int*   mbat = mask + ((size_t)b * kS + qbase) * kS;

    const int kg = tid >> 5, dg = tid & 31;   // V staging assignment

    // ---- T14 prefetch registers (48 total) ----
    float4 kreg[2][2];   // K: 2 chunks x 8 floats
    float4 vreg[4];      // V: one 4k x 4d block
    int4   mreg[4];      // mask: 4 int4 (128 rows x 32 ints / 256 thr)

    auto LOAD = [&](int kt0) {
        #pragma unroll
        for (int c = 0; c < 2; ++c) {
            int chunk = c * 256 + tid;
            int row = chunk >> 4, col8 = chunk & 15;
            const float4* ptr = (const float4*)(kbat + (size_t)(kt0 + row)*kD + col8*8);
            kreg[c][0] = ptr[0];
            kreg[c][1] = ptr[1];
        }
        #pragma unroll
        for (int r = 0; r < 4; ++r)
            vreg[r] = *(const float4*)(vbat + (size_t)(kt0 + kg*4 + r)*kD + dg*4);
        #pragma unroll
        for (int c = 0; c < 4; ++c) {
            int idx = c * 256 + tid;
            int mrow = idx >> 3, mc4 = idx & 7;
            mreg[c] = *(const int4*)(mbat + (size_t)mrow*kS + kt0 + mc4*4);
        }
    };

    auto STORE = [&]() {
        #pragma unroll
        for (int c = 0; c < 2; ++c) {
            int chunk = c * 256 + tid;
            int row = chunk >> 4, col8 = chunk & 15;
            uint4v pk = { cvt_pk(kreg[c][0].x, kreg[c][0].y), cvt_pk(kreg[c][0].z, kreg[c][0].w),
                          cvt_pk(kreg[c][1].x, kreg[c][1].y), cvt_pk(kreg[c][1].z, kreg[c][1].w) };
            *(uint4v*)(K_lds + row*256 + SWZ(col8*16, row)) = pk;
        }
        #pragma unroll
        for (int jj = 0; jj < 4; ++jj) {
            int d = dg * 4 + jj;             // VT: d 0..127, k-cols kg*4..+3
            int col = (d >> 6) * 64 + kg * 8;
            uint2v pk = { cvt_pk((&vreg[0].x)[jj], (&vreg[1].x)[jj]),
                          cvt_pk((&vreg[2].x)[jj], (&vreg[3].x)[jj]) };
            *(uint2v*)(VT_lds + (d & 63)*128 + (col ^ (KEYV(d) << 4))) = pk;
        }
        #pragma unroll
        for (int c = 0; c < 4; ++c) {
            int idx = c * 256 + tid;
            int mrow = idx >> 3, mc4 = idx & 7;
            unsigned pk = (unsigned)(mreg[c].x != 0)
                        | ((unsigned)(mreg[c].y != 0) << 8)
                        | ((unsigned)(mreg[c].z != 0) << 16)
                        | ((unsigned)(mreg[c].w != 0) << 24);
            *(unsigned*)(M_lds + mrow*MSTRIDE + mc4*4) = pk;
        }
    };

    LOAD(kbase);

    for (int t = 0; t < nrounds; ++t) {
        __syncthreads();
        STORE();
        __syncthreads();
        if (t + 1 < nrounds) LOAD(kbase + (t + 1) * KBLK);

        // ---- S^T = K · Q^T : z[qs][kt][i] = S[k=kt*16+lg*4+i][q=l15], kf shared across qs ----
        f32x4 z[2][2];
        #pragma unroll
        for (int qs = 0; qs < 2; ++qs)
            #pragma unroll
            for (int kt = 0; kt < 2; ++kt) z[qs][kt] = f32x4{0.f,0.f,0.f,0.f};
        #pragma unroll
        for (int kt = 0; kt < 2; ++kt) {
            bf16x8 kf[4];
            int krow = kt*16 + l15;
            #pragma unroll
            for (int kk = 0; kk < 4; ++kk)
                kf[kk] = *(const bf16x8*)(K_lds + krow*256 + SWZ(kk*64 + lg*16, krow));
            #pragma unroll
            for (int qs = 0; qs < 2; ++qs)
                #pragma unroll
                for (int kk = 0; kk < 4; ++kk)
                    z[qs][kt] = __builtin_amdgcn_mfma_f32_16x16x32_bf16(kf[kk], qf[qs][kk], z[qs][kt], 0, 0, 0);
        }

        // ---- mask + in-lane online softmax (log2 domain); P packs in-place for K=16 PV ----
        bf16x4 pfA[2], pfB[2];   // pfA = kt0 (kv 0-15), pfB = kt1 (kv 16-31)
        #pragma unroll
        for (int qs = 0; qs < 2; ++qs) {
            const int mrowb = (w*32 + qs*16 + l15) * MSTRIDE;
            float mx = kNegMax;
            #pragma unroll
            for (int kt = 0; kt < 2; ++kt) {
                unsigned nib = *(const unsigned*)(M_lds + mrowb + kt*16 + lg*4);
                #pragma unroll
                for (int i = 0; i < 4; ++i) {
                    float sv = ((nib >> (8*i)) & 0xFFu) ? kNegMax : z[qs][kt][i];
                    z[qs][kt][i] = sv;
                    mx = fmaxf(mx, sv);
                }
            }
            mx = fmaxf(mx, __shfl_xor(mx, 16));
            mx = fmaxf(mx, __shfl_xor(mx, 32));
            if (!__all(mx <= m_r[qs] + kDeferThr)) {       // wave-uniform branch
                float mnew = fmaxf(m_r[qs], mx);
                float corr = exp2f(m_r[qs] - mnew);
                l_r[qs] *= corr;
                #pragma unroll
                for (int d = 0; d < 8; ++d) acc[qs][d] *= corr;
                m_r[qs] = mnew;
            }
            float p00 = exp2f(z[qs][0][0] - m_r[qs]);
            float p01 = exp2f(z[qs][0][1] - m_r[qs]);
            float p02 = exp2f(z[qs][0][2] - m_r[qs]);
            float p03 = exp2f(z[qs][0][3] - m_r[qs]);
            float p10 = exp2f(z[qs][1][0] - m_r[qs]);
            float p11 = exp2f(z[qs][1][1] - m_r[qs]);
            float p12 = exp2f(z[qs][1][2] - m_r[qs]);
            float p13 = exp2f(z[qs][1][3] - m_r[qs]);
            float rs = ((p00 + p01) + (p02 + p03)) + ((p10 + p11) + (p12 + p13));
            rs += __shfl_xor(rs, 16);
            rs += __shfl_xor(rs, 32);
            l_r[qs] += rs;
            uint2v pa = { cvt_pk(p00, p01), cvt_pk(p02, p03) };   // B[k=lg*4+j][q=l15], kt0
            uint2v pb = { cvt_pk(p10, p11), cvt_pk(p12, p13) };   // kt1
            pfA[qs] = __builtin_bit_cast(bf16x4, pa);
            pfB[qs] = __builtin_bit_cast(bf16x4, pb);
        }

        // ---- O^T += V^T · P^T as two K=16 MFMAs (no P LDS, no cross-lane) ----
        #pragma unroll
        for (int dblk = 0; dblk < 8; ++dblk) {
            int d = dblk*16 + l15;
            int rowb = (d & 63) * 128;
            int half = (d >> 6) * 64;
            int key = KEYV(d) << 4;
            bf16x4 vf0 = *(const bf16x4*)(VT_lds + rowb + ((half + lg*8) ^ key));        // kv lg*4..+3
            bf16x4 vf1 = *(const bf16x4*)(VT_lds + rowb + ((half + 32 + lg*8) ^ key));   // kv 16+lg*4..+3
            #pragma unroll
            for (int qs = 0; qs < 2; ++qs) {
                acc[qs][dblk] = mfma16(vf0, pfA[qs], acc[qs][dblk]);
                acc[qs][dblk] = mfma16(vf1, pfB[qs], acc[qs][dblk]);
            }
        }
    }

    if (SPLIT == 1) {
        #pragma unroll
        for (int qs = 0; qs < 2; ++qs) {
            float inv = 1.0f / l_r[qs];
            float* op = out + ((size_t)(b*kS + qbase + w*32 + qs*16 + l15)) * kD;
            #pragma unroll
            for (int dblk = 0; dblk < 8; ++dblk) {
                float4 r;
                r.x = acc[qs][dblk][0] * inv;
                r.y = acc[qs][dblk][1] * inv;
                r.z = acc[qs][dblk][2] * inv;
                r.w = acc[qs][dblk][3] * inv;
                *(float4*)(op + dblk*16 + lg*4) = r;
            }
        }
    } else {
        const int half = (kbase != 0);
        #pragma unroll
        for (int qs = 0; qs < 2; ++qs) {
            const size_t row = (size_t)half * (kB*kS) + (size_t)b*kS + qbase + w*32 + qs*16 + l15;
            float* op = ws + row * kD;
            #pragma unroll
            for (int dblk = 0; dblk < 8; ++dblk) {
                float4 r;
                r.x = acc[qs][dblk][0]; r.y = acc[qs][dblk][1];
                r.z = acc[qs][dblk][2]; r.w = acc[qs][dblk][3];
                *(float4*)(op + dblk*16 + lg*4) = r;
            }
            if (lg == 0) {
                float* ml = ws + (size_t)2*kB*kS*kD;
                ml[row*2 + 0] = m_r[qs];
                ml[row*2 + 1] = l_r[qs];
            }
        }
    }
}

// merge the two k-halves (m is log2-domain): out = (o0*e0 + o1*e1) / (l0*e0 + l1*e1)
__global__ __launch_bounds__(NTHREADS)
void attn_merge(const float* __restrict__ ws, float* __restrict__ out)
{
    const float* ml = ws + (size_t)2*kB*kS*kD;
    const int tid = threadIdx.x;
    const size_t r = (size_t)blockIdx.x * 8 + (tid >> 5);
    const int c = (tid & 31) * 4;
    float m0 = ml[r*2 + 0],               l0 = ml[r*2 + 1];
    float m1 = ml[((size_t)kB*kS + r)*2], l1 = ml[((size_t)kB*kS + r)*2 + 1];
    float mS = fmaxf(m0, m1);
    float e0 = exp2f(m0 - mS), e1 = exp2f(m1 - mS);
    float inv = 1.0f / (l0*e0 + l1*e1);
    float4 o0 = *(const float4*)(ws + r*kD + c);
    float4 o1 = *(const float4*)(ws + (size_t)kB*kS*kD + r*kD + c);
    float4 rr;
    rr.x = (o0.x*e0 + o1.x*e1) * inv;
    rr.y = (o0.y*e0 + o1.y*e1) * inv;
    rr.z = (o0.z*e0 + o1.z*e1) * inv;
    rr.w = (o0.w*e0 + o1.w*e1) * inv;
    *(float4*)(out + r*kD + c) = rr;
}

extern "C" void kernel_launch(void* const* d_in, const int* in_sizes, int n_in,
                              void* d_out, int out_size, void* d_ws, size_t ws_size,
                              hipStream_t stream) {
    const float* q = (const float*)d_in[0];
    const float* k = (const float*)d_in[1];
    const float* v = (const float*)d_in[2];
    const int* mask = (const int*)d_in[3];
    float* out = (float*)d_out;
    const size_t wsNeeded = (size_t)2*kB*kS*kD*4 + (size_t)2*kB*kS*2*4;
    if (ws_size >= wsNeeded) {
        attn_fwd<2><<<dim3(kB * (kS/QBLK) * 2), dim3(NTHREADS), 0, stream>>>(
            q, k, v, mask, out, (float*)d_ws);
        attn_merge<<<dim3(kB*kS/8), dim3(NTHREADS), 0, stream>>>((const float*)d_ws, out);
    } else {
        attn_fwd<1><<<dim3(kB * (kS/QBLK)), dim3(NTHREADS), 0, stream>>>(
            q, k, v, mask, out, nullptr);
    }
}